// Round 9
// baseline (247.234 us; speedup 1.0000x reference)
//
#include <hip/hip_runtime.h>

#define NHEADS 8
#define TQ 4
#define QH 16
#define QW 16
#define TK 4
#define KH 16
#define KW 16
#define DIM 64
#define BATCH 4

#define ROWS (BATCH * NHEADS * TQ * QH * QW)   // 32768
#define RPB 16                                  // rows per block; w == local row 0..15
#define EST 68                                  // emb/q LDS row stride (floats): 4-bank skew per row

// clang ext-vector type: bit-identical to float4 but accepted by
// __builtin_nontemporal_{load,store} (HIP_vector_type struct is not).
typedef float f4 __attribute__((ext_vector_type(4)));

// One block per 16 consecutive q-rows (same t,h; w == local row index r=0..15).
// out[row][tk*256+kh*16+kw] = scores[row][...] + dot(q_row, hemb[h-kh+15])
//                            + dot(q_row, wemb[w-kw+15]) + dot(q_row, temb[t-tk+3])
//
// Hot-path design (measured ladder r2-r7):
//  - ALL q/emb staged to LDS once (coalesced), ONE barrier before any score
//    load is issued (its implicit vmcnt(0) drain costs nothing there).
//  - Each wave owns 4 rows independently: 16 score loads in flight while the
//    wave's 144 bias dots run from LDS; rel slice is wave-private so the
//    write->read needs only lgkmcnt — NO barrier, NO global gathers in the
//    hot path.  (87 -> ~76 us vs the barrier structure.)
//  - A/B this round: CACHED score loads (r3 proved scores goes half-L3-
//    resident across timed iterations, FETCH 134->70 MB) + nt stores (out is
//    written once, never read; keeps the write stream from evicting scores).
__global__ __launch_bounds__(256) void relpos_stage_kernel(
    const float* __restrict__ query,   // [B,H,1024,64]
    const float* __restrict__ scores,  // [B,H,1024,1024]
    const float* __restrict__ hemb,    // [31,64]
    const float* __restrict__ wemb,    // [31,64]
    const float* __restrict__ temb,    // [7,64]
    float* __restrict__ out)           // [B,H,1024,1024]
{
    const int tid  = threadIdx.x;
    const int lane = tid & 63;
    const int wv   = tid >> 6;
    const int row0 = blockIdx.x * RPB;  // multiple of 16
    const int pos  = row0 & 1023;
    const int t = pos >> 8;
    const int h = (pos >> 4) & 15;      // same for all 16 rows; w == local row

    __shared__ float lds_q[RPB][EST];   // q rows, stride-68 (4-bank skew)
    __shared__ float lds_h[16][EST];    // hemb rows h..h+15 (index 15-j)
    __shared__ float lds_w[31][EST];    // all wemb rows
    __shared__ float lds_t[4][EST];     // temb rows t..t+3 (index 3-tk)
    __shared__ float rel[RPB][40];      // per row: [0:16) h, [16:32) w, [32:36) t

    // ---- Stage (coalesced f4; tiny, L2-hot sources) ---------------------
    {
        const f4* sq = (const f4*)(query + (size_t)row0 * DIM);   // 256 f4
        const f4* sh = (const f4*)(hemb + (size_t)h * DIM);       // 256 f4
        const f4* sw = (const f4*)wemb;                           // 496 f4
        const f4* st = (const f4*)(temb + (size_t)t * DIM);       // 64 f4
        {
            const int r = tid >> 4, c = tid & 15;
            *(f4*)&lds_q[r][4 * c] = sq[tid];
            *(f4*)&lds_h[r][4 * c] = sh[tid];
            *(f4*)&lds_w[r][4 * c] = sw[tid];
        }
        if (tid < 240) {
            const int k = 256 + tid;
            *(f4*)&lds_w[k >> 4][4 * (k & 15)] = sw[k];
        }
        if (tid < 64)
            *(f4*)&lds_t[tid >> 4][4 * (tid & 15)] = st[tid];
    }
    __syncthreads();   // only barrier; nothing else in flight -> drain is free

    // ---- Issue this wave's 16 score loads (4 rows x 4 f4/lane) ----------
    // CACHED: scores (134 MB) fits L3 and is re-read across timed
    // iterations; r3 measured FETCH_SIZE = 70 MB with cached loads.
    const size_t rbase = (size_t)(row0 + wv * 4) * 1024;
    f4 s[4][4];
#pragma unroll
    for (int r = 0; r < 4; ++r) {
        const f4* sp = (const f4*)(scores + rbase + (size_t)r * 1024);
#pragma unroll
        for (int i = 0; i < 4; ++i)
            s[r][i] = sp[lane + 64 * i];
    }

    // ---- 144 bias dots from LDS, overlapped with the loads above --------
    // Wave wv touches only rel rows 4wv..4wv+3 (write AND read) -> no barrier.
#pragma unroll
    for (int d0 = 0; d0 < 144; d0 += 64) {
        const int d = d0 + lane;
        if (d < 144) {
            const int rl  = d / 36;
            const int j   = d - rl * 36;
            const int row = wv * 4 + rl;      // block-local row == w
            const float* ep;
            if (j < 16)      ep = &lds_h[15 - j][0];
            else if (j < 32) ep = &lds_w[row - (j - 16) + 15][0];
            else             ep = &lds_t[3 - (j - 32)][0];
            const float* qp = &lds_q[row][0];
            float acc = 0.f;
#pragma unroll
            for (int c = 0; c < 16; ++c) {
                f4 qv = *(const f4*)(qp + 4 * c);
                f4 ev = *(const f4*)(ep + 4 * c);
                acc += qv.x * ev.x + qv.y * ev.y + qv.z * ev.z + qv.w * ev.w;
            }
            rel[row][j] = acc;
        }
    }

    // ---- Combine + nt store (col of f4 #i of row: 4*lane + 256*i) -------
    // tk == i, kh == lane>>2, kw0 == (4*lane)&15 — all static per lane.
    const int kh  = lane >> 2;
    const int kw0 = (lane << 2) & 15;
#pragma unroll
    for (int r = 0; r < 4; ++r) {
        const int row = wv * 4 + r;
        const float hv = rel[row][kh];
        const f4 tv  = *(const f4*)&rel[row][32];
        const f4 wv4 = *(const f4*)&rel[row][16 + kw0];
        f4* op = (f4*)(out + rbase + (size_t)r * 1024);
#pragma unroll
        for (int i = 0; i < 4; ++i) {
            f4 o = s[r][i] + (hv + tv[i]) + wv4;
            __builtin_nontemporal_store(o, op + lane + 64 * i);
        }
    }
}

extern "C" void kernel_launch(void* const* d_in, const int* in_sizes, int n_in,
                              void* d_out, int out_size, void* d_ws, size_t ws_size,
                              hipStream_t stream) {
    const float* query  = (const float*)d_in[0];
    const float* scores = (const float*)d_in[1];
    const float* hemb   = (const float*)d_in[2];
    const float* wemb   = (const float*)d_in[3];
    const float* temb   = (const float*)d_in[4];
    float* out = (float*)d_out;

    relpos_stage_kernel<<<dim3(ROWS / RPB), dim3(256), 0, stream>>>(
        query, scores, hemb, wemb, temb, out);
}

// Round 10
// 245.251 us; speedup vs baseline: 1.0081x; 1.0081x over previous
//
#include <hip/hip_runtime.h>

#define NHEADS 8
#define TQ 4
#define QH 16
#define QW 16
#define TK 4
#define KH 16
#define KW 16
#define DIM 64
#define BATCH 4

#define ROWS (BATCH * NHEADS * TQ * QH * QW)   // 32768
#define RPB 64                                  // rows per block
#define EST 68                                  // q/emb LDS row stride (floats), 272 B (16B-aligned)

// clang ext-vector type: bit-identical to float4 but accepted by
// __builtin_nontemporal_{load,store} (HIP_vector_type struct is not).
typedef float f4 __attribute__((ext_vector_type(4)));

// One block per 64 consecutive q-rows (row0 64-aligned => t fixed, h = h0+wv
// per wave, w = rr (block-local row & 15)). Wave wv owns rows [16wv,16wv+16):
// 4 epochs x 4 rows, epoch-level double-buffered so vmcnt NEVER drains to 0
// across the wave's life (the fill/copy µbench property; every one-shot
// variant measured 3.3-3.6 TB/s, write-only fill 6.6 TB/s).
//
// out[row][tk*256+kh*16+kw] = scores[row][...] + dot(q_row, hemb[h-kh+15])
//                            + dot(q_row, wemb[w-kw+15]) + dot(q_row, temb[t-tk+3])
//
// Config (measured): nt loads + nt stores (r7 best; r9 proved cached loads
// SLOWER despite halving HBM fetch -> not BW-bound). One barrier, before the
// stream; rel is wave-private (same-wave LDS write->read needs no barrier).
__global__ __launch_bounds__(256) void relpos_pipe_kernel(
    const float* __restrict__ query,   // [B,H,1024,64]
    const float* __restrict__ scores,  // [B,H,1024,1024]
    const float* __restrict__ hemb,    // [31,64]
    const float* __restrict__ wemb,    // [31,64]
    const float* __restrict__ temb,    // [7,64]
    float* __restrict__ out)           // [B,H,1024,1024]
{
    const int tid  = threadIdx.x;
    const int lane = tid & 63;
    const int wv   = tid >> 6;
    const int row0 = blockIdx.x * RPB;  // 64-aligned
    const int pos  = row0 & 1023;
    const int t  = pos >> 8;            // fixed for all 64 rows
    const int h0 = (pos >> 4) & 15;     // in {0,4,8,12}; row lr has h = h0 + (lr>>4)

    __shared__ float lds_q[RPB][EST];   // q rows (block-local)
    __shared__ float lds_h[19][EST];    // hemb rows h0..h0+18
    __shared__ float lds_w[31][EST];    // all wemb rows
    __shared__ float lds_t[4][EST];     // temb rows t..t+3
    __shared__ float rel[RPB][40];      // per row: [0:16) h, [16:32) w, [32:36) t

    // Per-lane output geometry: float col = 4*lane + 256*i  =>  tk=i,
    // kh = lane>>2, kw0 = (lane&3)*4.
    const int kh  = lane >> 2;
    const int kw0 = (lane & 3) << 2;

    const f4* sp = (const f4*)scores + (size_t)(row0 + wv * 16) * 256;
    f4*       op = (f4*)out          + (size_t)(row0 + wv * 16) * 256;

    f4 A[4][4], B[4][4];

    auto epoch_load = [&](f4 buf[4][4], int e) {
#pragma unroll
        for (int r = 0; r < 4; ++r)
#pragma unroll
            for (int i = 0; i < 4; ++i)
                buf[r][i] = __builtin_nontemporal_load(sp + (e * 4 + r) * 256 + lane + 64 * i);
    };
    auto epoch_store = [&](f4 buf[4][4], int e) {
#pragma unroll
        for (int r = 0; r < 4; ++r) {
            const int lr = wv * 16 + e * 4 + r;
            const float hv = rel[lr][kh];
            const f4 tv = *(const f4*)&rel[lr][32];
            const f4 w4 = *(const f4*)&rel[lr][16 + kw0];
#pragma unroll
            for (int i = 0; i < 4; ++i) {
                f4 o = buf[r][i] + (hv + tv[i]) + w4;
                __builtin_nontemporal_store(o, op + (e * 4 + r) * 256 + lane + 64 * i);
            }
        }
    };

    // ---- Epochs 0,1 issued first: 32 f4/lane in flight under staging+dots.
    epoch_load(A, 0);
    epoch_load(B, 1);

    // ---- Stage q/emb to LDS (coalesced f4; sources tiny and L2-hot) -----
    {
        const f4* sq = (const f4*)(query + (size_t)row0 * DIM);    // 1024 f4
        const f4* sh = (const f4*)(hemb + (size_t)h0 * DIM);       // 304 f4
        const f4* sw = (const f4*)wemb;                            // 496 f4
        const f4* st = (const f4*)(temb + (size_t)t * DIM);        // 64 f4
#pragma unroll
        for (int k0 = 0; k0 < 1024; k0 += 256) {
            const int k = k0 + tid;
            *(f4*)&lds_q[k >> 4][4 * (k & 15)] = sq[k];
        }
        if (tid < 304 - 256) { const int k = 256 + tid; *(f4*)&lds_h[k >> 4][4 * (k & 15)] = sh[k]; }
        { const int k = tid; if (k < 304) {} }
        {
            const int k = tid;
            if (k < 256) *(f4*)&lds_h[k >> 4][4 * (k & 15)] = sh[k];
        }
        {
            const int k = tid;
            *(f4*)&lds_w[k >> 4][4 * (k & 15)] = sw[k];
            if (k < 496 - 256) { const int k2 = 256 + k; *(f4*)&lds_w[k2 >> 4][4 * (k2 & 15)] = sw[k2]; }
        }
        if (tid < 64) *(f4*)&lds_t[tid >> 4][4 * (tid & 15)] = st[tid];
    }
    __syncthreads();   // only barrier; drains staging (and epochs 0,1 — data needed soon anyway)

    // ---- Wave-private bias dots: 576 dots (16 rows x 36), 9 per lane ----
    for (int d = lane; d < 576; d += 64) {
        const int rr = d / 36;            // wave-local row 0..15 == w
        const int j  = d - rr * 36;
        const int lr = wv * 16 + rr;
        const float* ep;
        if (j < 16)      ep = &lds_h[wv + 15 - j][0];
        else if (j < 32) ep = &lds_w[rr - (j - 16) + 15][0];
        else             ep = &lds_t[3 - (j - 32)][0];
        const float* qp = &lds_q[lr][0];
        float acc = 0.f;
#pragma unroll
        for (int c = 0; c < 16; ++c) {
            f4 qv = *(const f4*)(qp + 4 * c);
            f4 ev = *(const f4*)(ep + 4 * c);
            acc += qv.x * ev.x + qv.y * ev.y + qv.z * ev.z + qv.w * ev.w;
        }
        rel[lr][j] = acc;
    }
    // rel write->read below is same-wave: LDS ops from one wave are ordered;
    // compiler inserts the lgkmcnt (r7 relied on this, passed).

    // ---- Pipelined epochs: loads for e+1/e+2 always in flight -----------
    epoch_store(A, 0);
    epoch_load (A, 2);     // register reuse of A pins pipeline depth
    epoch_store(B, 1);
    epoch_load (B, 3);
    epoch_store(A, 2);
    epoch_store(B, 3);
}

extern "C" void kernel_launch(void* const* d_in, const int* in_sizes, int n_in,
                              void* d_out, int out_size, void* d_ws, size_t ws_size,
                              hipStream_t stream) {
    const float* query  = (const float*)d_in[0];
    const float* scores = (const float*)d_in[1];
    const float* hemb   = (const float*)d_in[2];
    const float* wemb   = (const float*)d_in[3];
    const float* temb   = (const float*)d_in[4];
    float* out = (float*)d_out;

    relpos_pipe_kernel<<<dim3(ROWS / RPB), dim3(256), 0, stream>>>(
        query, scores, hemb, wemb, temb, out);
}

// Round 11
// 245.196 us; speedup vs baseline: 1.0083x; 1.0002x over previous
//
#include <hip/hip_runtime.h>

#define NHEADS 8
#define TQ 4
#define QH 16
#define QW 16
#define TK 4
#define KH 16
#define KW 16
#define DIM 64
#define BATCH 4

#define ROWS (BATCH * NHEADS * TQ * QH * QW)   // 32768
#define RPB 16                                  // rows per block in pass A (r7 structure)
#define EST 68                                  // q/emb LDS row stride (floats): 4-bank skew
// workspace: THp[ROWS][64] then W[ROWS][16]  -> 80 floats/row = 10.49 MB
#define WS_BYTES_NEEDED ((size_t)ROWS * 80 * sizeof(float))

// clang ext-vector type: bit-identical to float4 but accepted by
// __builtin_nontemporal_{load,store} (HIP_vector_type struct is not).
typedef float f4 __attribute__((ext_vector_type(4)));

// ---------------------------------------------------------------------------
// Pass A: r7's proven stage+dot machinery, output = bias tables (no stream).
//   THp[row][kh*4+tk] = dot(q,hemb[h-kh+15]) + dot(q,temb[t-tk+3])
//   W  [row][kw]      = dot(q,wemb[w-kw+15])
// THp is permuted so pass B's lane l reads ONE f4 (kh=l>>2, tk=0..3).
// ---------------------------------------------------------------------------
__global__ __launch_bounds__(256) void relpos_bias16(
    const float* __restrict__ query,   // [B,H,1024,64]
    const float* __restrict__ hemb,    // [31,64]
    const float* __restrict__ wemb,    // [31,64]
    const float* __restrict__ temb,    // [7,64]
    float* __restrict__ thp,           // [ROWS,64]
    float* __restrict__ wt)            // [ROWS,16]
{
    const int tid  = threadIdx.x;
    const int lane = tid & 63;
    const int wv   = tid >> 6;
    const int row0 = blockIdx.x * RPB;  // multiple of 16
    const int pos  = row0 & 1023;
    const int t = pos >> 8;
    const int h = (pos >> 4) & 15;      // same for all 16 rows; w == local row

    __shared__ float lds_q[RPB][EST];
    __shared__ float lds_h[16][EST];
    __shared__ float lds_w[31][EST];
    __shared__ float lds_t[4][EST];
    __shared__ float rel[RPB][40];      // [0:16) h, [16:32) w, [32:36) t

    // ---- Stage q/emb (coalesced f4; tiny, L2-hot sources) ---------------
    {
        const f4* sq = (const f4*)(query + (size_t)row0 * DIM);   // 256 f4
        const f4* sh = (const f4*)(hemb + (size_t)h * DIM);       // 256 f4
        const f4* sw = (const f4*)wemb;                           // 496 f4
        const f4* st = (const f4*)(temb + (size_t)t * DIM);       // 64 f4
        {
            const int r = tid >> 4, c = tid & 15;
            *(f4*)&lds_q[r][4 * c] = sq[tid];
            *(f4*)&lds_h[r][4 * c] = sh[tid];
            *(f4*)&lds_w[r][4 * c] = sw[tid];
        }
        if (tid < 240) {
            const int k = 256 + tid;
            *(f4*)&lds_w[k >> 4][4 * (k & 15)] = sw[k];
        }
        if (tid < 64)
            *(f4*)&lds_t[tid >> 4][4 * (tid & 15)] = st[tid];
    }
    __syncthreads();   // only barrier

    // ---- Wave-private bias dots (rows 4wv..4wv+3), as in r7 -------------
#pragma unroll
    for (int d0 = 0; d0 < 144; d0 += 64) {
        const int d = d0 + lane;
        if (d < 144) {
            const int rl  = d / 36;
            const int j   = d - rl * 36;
            const int row = wv * 4 + rl;      // block-local row == w
            const float* ep;
            if (j < 16)      ep = &lds_h[15 - j][0];
            else if (j < 32) ep = &lds_w[row - (j - 16) + 15][0];
            else             ep = &lds_t[3 - (j - 32)][0];
            const float* qp = &lds_q[row][0];
            float acc = 0.f;
#pragma unroll
            for (int c = 0; c < 16; ++c) {
                f4 qv = *(const f4*)(qp + 4 * c);
                f4 ev = *(const f4*)(ep + 4 * c);
                acc += qv.x * ev.x + qv.y * ev.y + qv.z * ev.z + qv.w * ev.w;
            }
            rel[row][j] = acc;
        }
    }
    // same-wave LDS write->read below: compiler-ordered (lgkmcnt), no barrier.

    // ---- Table writes (wave-private rows, coalesced) --------------------
    float* tb = thp + (size_t)(row0 + wv * 4) * 64;
    float* wb = wt  + (size_t)(row0 + wv * 4) * 16;
#pragma unroll
    for (int r = 0; r < 4; ++r) {
        const int lr = wv * 4 + r;
        // THp[row][l] with l = kh*4+tk  ->  rel_h[l>>2] + rel_t[l&3]
        tb[r * 64 + lane] = rel[lr][lane >> 2] + rel[lr][32 + (lane & 3)];
        if (lane < 16) wb[r * 16 + lane] = rel[lr][16 + lane];
    }
}

// ---------------------------------------------------------------------------
// Pass B: pure stream — no LDS, no barrier, long-lived waves, depth-2 row
// double buffer. Wave gw owns rows [8gw, 8gw+8); lane l owns f4s l+64i.
//   col = 4l + 256i  =>  tk = i, kh = l>>2, kw0 = 4(l&3)
//   bias = THp4[row][l>>2][i] + W4[row][l&3][j]
// scores: nt loads (r9 A/B: nt beats cached). out: nt stores.
// tables: cached loads (written by pass A this iteration -> L2/L3 hot).
// ---------------------------------------------------------------------------
__global__ __launch_bounds__(256) void relpos_stream_kernel(
    const float* __restrict__ scores,  // [B,H,1024,1024]
    const float* __restrict__ thp,     // [ROWS,64]
    const float* __restrict__ wt,      // [ROWS,16]
    float* __restrict__ out)           // [B,H,1024,1024]
{
    const int lane = threadIdx.x & 63;
    const int wv   = threadIdx.x >> 6;
    const size_t row0 = ((size_t)blockIdx.x * 4 + wv) * 8;   // 8 rows per wave

    const f4* sp = (const f4*)scores + row0 * 256;
    f4*       op = (f4*)out          + row0 * 256;
    const int khq = lane >> 2;
    const int wq  = lane & 3;

    f4 sA0, sA1, sA2, sA3, thA, wA;
    f4 sB0, sB1, sB2, sB3, thB, wB;

#define LDROW(S0, S1, S2, S3, TH, W, r)                                        \
    {                                                                          \
        const f4* p = sp + (r) * 256;                                          \
        S0 = __builtin_nontemporal_load(p + lane);                             \
        S1 = __builtin_nontemporal_load(p + lane + 64);                        \
        S2 = __builtin_nontemporal_load(p + lane + 128);                       \
        S3 = __builtin_nontemporal_load(p + lane + 192);                       \
        TH = *((const f4*)(thp + (row0 + (r)) * 64) + khq);                    \
        W  = *((const f4*)(wt  + (row0 + (r)) * 16) + wq);                     \
    }
#define STROW(S0, S1, S2, S3, TH, W, r)                                        \
    {                                                                          \
        f4* p = op + (r) * 256;                                                \
        __builtin_nontemporal_store(S0 + TH[0] + W, p + lane);                 \
        __builtin_nontemporal_store(S1 + TH[1] + W, p + lane + 64);            \
        __builtin_nontemporal_store(S2 + TH[2] + W, p + lane + 128);           \
        __builtin_nontemporal_store(S3 + TH[3] + W, p + lane + 192);           \
    }

    LDROW(sA0, sA1, sA2, sA3, thA, wA, 0)
#pragma unroll
    for (int k = 0; k < 4; ++k) {
        LDROW(sB0, sB1, sB2, sB3, thB, wB, 2 * k + 1)
        STROW(sA0, sA1, sA2, sA3, thA, wA, 2 * k)
        if (2 * k + 2 < 8)
            LDROW(sA0, sA1, sA2, sA3, thA, wA, 2 * k + 2)
        STROW(sB0, sB1, sB2, sB3, thB, wB, 2 * k + 1)
    }
#undef LDROW
#undef STROW
}

// ---------------------------------------------------------------------------
// Fallback: exact r7 fused kernel (best measured: ~76 us), used if ws small.
// ---------------------------------------------------------------------------
__global__ __launch_bounds__(256) void relpos_stage_kernel(
    const float* __restrict__ query,
    const float* __restrict__ scores,
    const float* __restrict__ hemb,
    const float* __restrict__ wemb,
    const float* __restrict__ temb,
    float* __restrict__ out)
{
    const int tid  = threadIdx.x;
    const int lane = tid & 63;
    const int wv   = tid >> 6;
    const int row0 = blockIdx.x * RPB;
    const int pos  = row0 & 1023;
    const int t = pos >> 8;
    const int h = (pos >> 4) & 15;

    __shared__ float lds_q[RPB][EST];
    __shared__ float lds_h[16][EST];
    __shared__ float lds_w[31][EST];
    __shared__ float lds_t[4][EST];
    __shared__ float rel[RPB][40];

    {
        const f4* sq = (const f4*)(query + (size_t)row0 * DIM);
        const f4* sh = (const f4*)(hemb + (size_t)h * DIM);
        const f4* sw = (const f4*)wemb;
        const f4* st = (const f4*)(temb + (size_t)t * DIM);
        {
            const int r = tid >> 4, c = tid & 15;
            *(f4*)&lds_q[r][4 * c] = sq[tid];
            *(f4*)&lds_h[r][4 * c] = sh[tid];
            *(f4*)&lds_w[r][4 * c] = sw[tid];
        }
        if (tid < 240) {
            const int k = 256 + tid;
            *(f4*)&lds_w[k >> 4][4 * (k & 15)] = sw[k];
        }
        if (tid < 64)
            *(f4*)&lds_t[tid >> 4][4 * (tid & 15)] = st[tid];
    }
    __syncthreads();

    const size_t rbase = (size_t)(row0 + wv * 4) * 1024;
    f4 s[4][4];
#pragma unroll
    for (int r = 0; r < 4; ++r) {
        const f4* sp = (const f4*)(scores + rbase + (size_t)r * 1024);
#pragma unroll
        for (int i = 0; i < 4; ++i)
            s[r][i] = __builtin_nontemporal_load(sp + lane + 64 * i);
    }

#pragma unroll
    for (int d0 = 0; d0 < 144; d0 += 64) {
        const int d = d0 + lane;
        if (d < 144) {
            const int rl  = d / 36;
            const int j   = d - rl * 36;
            const int row = wv * 4 + rl;
            const float* ep;
            if (j < 16)      ep = &lds_h[15 - j][0];
            else if (j < 32) ep = &lds_w[row - (j - 16) + 15][0];
            else             ep = &lds_t[3 - (j - 32)][0];
            const float* qp = &lds_q[row][0];
            float acc = 0.f;
#pragma unroll
            for (int c = 0; c < 16; ++c) {
                f4 qv = *(const f4*)(qp + 4 * c);
                f4 ev = *(const f4*)(ep + 4 * c);
                acc += qv.x * ev.x + qv.y * ev.y + qv.z * ev.z + qv.w * ev.w;
            }
            rel[row][j] = acc;
        }
    }

    const int kh  = lane >> 2;
    const int kw0 = (lane << 2) & 15;
#pragma unroll
    for (int r = 0; r < 4; ++r) {
        const int row = wv * 4 + r;
        const float hv = rel[row][kh];
        const f4 tv  = *(const f4*)&rel[row][32];
        const f4 wv4 = *(const f4*)&rel[row][16 + kw0];
        f4* op = (f4*)(out + rbase + (size_t)r * 1024);
#pragma unroll
        for (int i = 0; i < 4; ++i) {
            f4 o = s[r][i] + (hv + tv[i]) + wv4;
            __builtin_nontemporal_store(o, op + lane + 64 * i);
        }
    }
}

extern "C" void kernel_launch(void* const* d_in, const int* in_sizes, int n_in,
                              void* d_out, int out_size, void* d_ws, size_t ws_size,
                              hipStream_t stream) {
    const float* query  = (const float*)d_in[0];
    const float* scores = (const float*)d_in[1];
    const float* hemb   = (const float*)d_in[2];
    const float* wemb   = (const float*)d_in[3];
    const float* temb   = (const float*)d_in[4];
    float* out = (float*)d_out;

    if (d_ws != nullptr && ws_size >= WS_BYTES_NEEDED) {
        float* thp = (float*)d_ws;                         // [ROWS][64]
        float* wt  = thp + (size_t)ROWS * 64;              // [ROWS][16]
        relpos_bias16<<<dim3(ROWS / RPB), dim3(256), 0, stream>>>(
            query, hemb, wemb, temb, thp, wt);
        relpos_stream_kernel<<<dim3(ROWS / 32), dim3(256), 0, stream>>>(
            scores, thp, wt, out);
    } else {
        relpos_stage_kernel<<<dim3(ROWS / RPB), dim3(256), 0, stream>>>(
            query, scores, hemb, wemb, temb, out);
    }
}

// Round 12
// 235.710 us; speedup vs baseline: 1.0489x; 1.0402x over previous
//
#include <hip/hip_runtime.h>

#define NHEADS 8
#define TQ 4
#define QH 16
#define QW 16
#define TK 4
#define KH 16
#define KW 16
#define DIM 64
#define BATCH 4

#define ROWS (BATCH * NHEADS * TQ * QH * QW)   // 32768
#define RPB 16                                  // rows per block; w == local row 0..15
#define EST 68                                  // emb/q LDS row stride (floats): 4-bank skew per row

// clang ext-vector type: bit-identical to float4 but accepted by
// __builtin_nontemporal_{load,store} (HIP_vector_type struct is not).
typedef float f4 __attribute__((ext_vector_type(4)));

// Best measured configuration (r7: headline 237.5 us, kernel ~76 us).
//
// One block per 16 consecutive q-rows (same t,h; w == local row index r=0..15).
// out[row][tk*256+kh*16+kw] = scores[row][...] + dot(q_row, hemb[h-kh+15])
//                            + dot(q_row, wemb[w-kw+15]) + dot(q_row, temb[t-tk+3])
//
// Measured ladder (kernel-only):
//   depth-1 loop 120us | depth-8 111us | depth-4+barrier 87us | epoch-pipe ~86us
//   cached-loads ~86us (1/2 HBM fetch, no gain) | two-pass copy-shape ~84us
//   THIS (barrier-free fused, nt/nt) ~76us  == 3.5 TB/s mixed-stream envelope
//
// Design:
//  - ALL q/emb staged to LDS once (coalesced), ONE barrier before any score
//    load is issued (its implicit vmcnt(0) drain costs nothing there).
//  - Each wave owns 4 rows independently: 16 nt score loads in flight while
//    the wave's 144 bias dots run from LDS; rel slice is wave-private so the
//    write->read needs only lgkmcnt (compiler-inserted) — NO barrier, NO
//    global gathers in the hot path.
//  - nt loads (r9 A/B: cached loads halve FETCH but run SLOWER -> not
//    BW-bound) + nt stores (WRITE_SIZE stays exactly 134 MB, no allocate).
__global__ __launch_bounds__(256) void relpos_stage_kernel(
    const float* __restrict__ query,   // [B,H,1024,64]
    const float* __restrict__ scores,  // [B,H,1024,1024]
    const float* __restrict__ hemb,    // [31,64]
    const float* __restrict__ wemb,    // [31,64]
    const float* __restrict__ temb,    // [7,64]
    float* __restrict__ out)           // [B,H,1024,1024]
{
    const int tid  = threadIdx.x;
    const int lane = tid & 63;
    const int wv   = tid >> 6;
    const int row0 = blockIdx.x * RPB;  // multiple of 16
    const int pos  = row0 & 1023;
    const int t = pos >> 8;
    const int h = (pos >> 4) & 15;      // same for all 16 rows; w == local row

    __shared__ float lds_q[RPB][EST];   // q rows, stride-68 (4-bank skew)
    __shared__ float lds_h[16][EST];    // hemb rows h..h+15 (index 15-j)
    __shared__ float lds_w[31][EST];    // all wemb rows
    __shared__ float lds_t[4][EST];     // temb rows t..t+3 (index 3-tk)
    __shared__ float rel[RPB][40];      // per row: [0:16) h, [16:32) w, [32:36) t

    // ---- Stage (coalesced f4; tiny, L2-hot sources) ---------------------
    {
        const f4* sq = (const f4*)(query + (size_t)row0 * DIM);   // 256 f4
        const f4* sh = (const f4*)(hemb + (size_t)h * DIM);       // 256 f4
        const f4* sw = (const f4*)wemb;                           // 496 f4
        const f4* st = (const f4*)(temb + (size_t)t * DIM);       // 64 f4
        {
            const int r = tid >> 4, c = tid & 15;
            *(f4*)&lds_q[r][4 * c] = sq[tid];
            *(f4*)&lds_h[r][4 * c] = sh[tid];
            *(f4*)&lds_w[r][4 * c] = sw[tid];
        }
        if (tid < 240) {
            const int k = 256 + tid;
            *(f4*)&lds_w[k >> 4][4 * (k & 15)] = sw[k];
        }
        if (tid < 64)
            *(f4*)&lds_t[tid >> 4][4 * (tid & 15)] = st[tid];
    }
    __syncthreads();   // only barrier; nothing else in flight -> drain is free

    // ---- Issue this wave's 16 nt score loads (4 rows x 4 f4/lane) -------
    const size_t rbase = (size_t)(row0 + wv * 4) * 1024;
    f4 s[4][4];
#pragma unroll
    for (int r = 0; r < 4; ++r) {
        const f4* sp = (const f4*)(scores + rbase + (size_t)r * 1024);
#pragma unroll
        for (int i = 0; i < 4; ++i)
            s[r][i] = __builtin_nontemporal_load(sp + lane + 64 * i);
    }

    // ---- 144 bias dots from LDS, overlapped with the loads above --------
    // Wave wv touches only rel rows 4wv..4wv+3 (write AND read) -> no barrier.
#pragma unroll
    for (int d0 = 0; d0 < 144; d0 += 64) {
        const int d = d0 + lane;
        if (d < 144) {
            const int rl  = d / 36;
            const int j   = d - rl * 36;
            const int row = wv * 4 + rl;      // block-local row == w
            const float* ep;
            if (j < 16)      ep = &lds_h[15 - j][0];
            else if (j < 32) ep = &lds_w[row - (j - 16) + 15][0];
            else             ep = &lds_t[3 - (j - 32)][0];
            const float* qp = &lds_q[row][0];
            float acc = 0.f;
#pragma unroll
            for (int c = 0; c < 16; ++c) {
                f4 qv = *(const f4*)(qp + 4 * c);
                f4 ev = *(const f4*)(ep + 4 * c);
                acc += qv.x * ev.x + qv.y * ev.y + qv.z * ev.z + qv.w * ev.w;
            }
            rel[row][j] = acc;
        }
    }

    // ---- Combine + nt store (col of f4 #i of row: 4*lane + 256*i) -------
    // tk == i, kh == lane>>2, kw0 == (4*lane)&15 — all static per lane.
    const int kh  = lane >> 2;
    const int kw0 = (lane << 2) & 15;
#pragma unroll
    for (int r = 0; r < 4; ++r) {
        const int row = wv * 4 + r;
        const float hv = rel[row][kh];
        const f4 tv  = *(const f4*)&rel[row][32];
        const f4 wv4 = *(const f4*)&rel[row][16 + kw0];
        f4* op = (f4*)(out + rbase + (size_t)r * 1024);
#pragma unroll
        for (int i = 0; i < 4; ++i) {
            f4 o = s[r][i] + (hv + tv[i]) + wv4;
            __builtin_nontemporal_store(o, op + lane + 64 * i);
        }
    }
}

extern "C" void kernel_launch(void* const* d_in, const int* in_sizes, int n_in,
                              void* d_out, int out_size, void* d_ws, size_t ws_size,
                              hipStream_t stream) {
    const float* query  = (const float*)d_in[0];
    const float* scores = (const float*)d_in[1];
    const float* hemb   = (const float*)d_in[2];
    const float* wemb   = (const float*)d_in[3];
    const float* temb   = (const float*)d_in[4];
    float* out = (float*)d_out;

    relpos_stage_kernel<<<dim3(ROWS / RPB), dim3(256), 0, stream>>>(
        query, scores, hemb, wemb, temb, out);
}